// Round 8
// baseline (133.939 us; speedup 1.0000x reference)
//
#include <hip/hip_runtime.h>
#include <hip/hip_bf16.h>

// KAN layer: out = einsum('bik,jik->bj', rbf(x), W) + silu(x)@Wb^T, then LN.
// GEMM view: C[4096,512] = A[4096,8704] * B[512,8704]^T in bf16 MFMA, where
// A = [rbf basis(x) | silu(x)]. A is NOT materialized: basis (k<8192) is
// computed in-GEMM from x; silu (4096x512 bf16 = 4.2 MB) is pre-materialized
// and reg-staged (z=7 tiles only).
//
// R7 post-mortem: fusion passed but gemm 45.4->52.4us. SQ_LDS_BANK_CONFLICT
// 0 -> 1.1M: basis ds_write_b128 at row stride 128 B === 0 mod 32 banks ->
// every row starts at bank 0; the chunk-XOR varied too few lane bits (8
// lanes/column/instr). Plus ~2.3K cyc/SIMD/tile of basis VALU all in ph3.
// R8: (1) pad As rows to 72 elems (144 B) -> bank base (row*9+c)%8 varies
// per row; enumeration: basis writes, silu writes, A reads all <=2 lanes/
// bank-group = free. XOR dropped on A (padding subsumes it). gll16 can't
// target padded LDS (m173) -> silu tiles reg-stage (load ph2, ds_write ph3,
// branch-disjoint with basis path so regs share). (2) basis split: x-col
// e=0 in ph2, e=1 in ph3 -> half the VALU per phase, two MFMA windows to
// hide under. B path (gll16+XOR+tile-local k1) and sync structure unchanged
// from passing R7.
//
// d_ws layout (uses 46.7 MB of the 113.7 MB ws):
//   Asilu bf16 [4096][512]   @ 0          ( 4,194,304 B)  silu(x)
//   Bm    bf16 [512][8704]   @ 4194304    ( 8,912,896 B)  Bm = [W | Wb]
//   Cp    bf16 [8][4096][512]@ 13107200   (33,554,432 B)  split-K partials

typedef __bf16 bf16x8 __attribute__((ext_vector_type(8)));
typedef __bf16 bf16x4 __attribute__((ext_vector_type(4)));
typedef float  f32x4  __attribute__((ext_vector_type(4)));

#define KT 8704            // total K = 512*16 + 512
#define SPLITS 8
#define KS (KT / SPLITS)   // 1088 per z-block
#define NT2 (KS / 64)      // 17 K-tiles of BK=64
#define CPE (4096 * 512)   // elements per partial
#define AP 72              // padded A row stride (elems): 64 + 8
#define ATILEA (256 * AP)  // one A tile slot: 256 rows x 72, elems (36,864 B)
#define ATILEB (256 * 64)  // one B tile slot: 256 rows x 64, elems (32,768 B)

__device__ __forceinline__ void gll16(const __bf16* g, __bf16* l) {
    __builtin_amdgcn_global_load_lds(
        (const __attribute__((address_space(1))) void*)g,
        (__attribute__((address_space(3))) void*)l, 16, 0, 0);
}

// ---- kernel 1: Asilu = silu(x) (bf16), Bm = [W | Wb] (bf16) ---------------
__global__ void prep_AB(const float* __restrict__ x, const float* __restrict__ W,
                        const float* __restrict__ Wb, __bf16* __restrict__ Asilu,
                        __bf16* __restrict__ B) {
    if (blockIdx.x < 1024) {                     // silu: 8 elems/thread
        int t = blockIdx.x * 256 + threadIdx.x;  // 0 .. 262143
        int e = t * 8;
        float4 v0 = *(const float4*)&x[e];
        float4 v1 = *(const float4*)&x[e + 4];
        float vs[8] = {v0.x, v0.y, v0.z, v0.w, v1.x, v1.y, v1.z, v1.w};
        bf16x8 o;
#pragma unroll
        for (int j = 0; j < 8; ++j) o[j] = (__bf16)(vs[j] / (1.0f + __expf(-vs[j])));
        *(bf16x8*)&Asilu[e] = o;
    } else {                                     // B-part: cast W|Wb, 4 elems/thread
        int t = (blockIdx.x - 1024) * 256 + threadIdx.x;  // 0 .. 512*2176
        int j = t / 2176;
        int c = (t - j * 2176) * 4;
        float4 v;
        if (c < 8192) v = *(const float4*)&W[(size_t)j * 8192 + c];
        else          v = *(const float4*)&Wb[(size_t)j * 512 + (c - 8192)];
        bf16x4 o;
        o[0] = (__bf16)v.x; o[1] = (__bf16)v.y; o[2] = (__bf16)v.z; o[3] = (__bf16)v.w;
        *(bf16x4*)&B[(size_t)j * KT + c] = o;
    }
}

// ---- kernel 2: fused split-K GEMM, 256x256 tile, 8 waves, BK=64, 4-phase --
// Per K-tile: ph0 {ds_read a0-3,b ks0; 2 gll16 B(u+1); x-load} -> bar ->
//             ph1 {a4-7 ks0; 2 gll16 B(u+1)} -> bar ->
//             ph2 {a0-3,b ks1; basis e=0 OR silu reg-loads} -> bar ->
//             ph3 {a4-7 ks1; basis e=1 OR silu ds_writes} -> __syncthreads().
// setprio(1) around each 16-MFMA cluster. All staging targets slot^1 (last
// read at tile u-1, drained by its __syncthreads -> WAR-safe). Tile-end
// __syncthreads publishes the A ds_writes and drains the B DMA.
//
// LDS layouts: As padded [256][72] per slot, chunk c (k in [c*8,c*8+8)) at
// row*72 + c*8 (no XOR; bank base (row*9+c)%8 spreads rows). Bs unpadded
// [256][64] with chunk XOR c^((row>>1)&7) for the gll16 path; reads
// de-swizzle with (q or 4+q)^((r16>>1)&7). All accesses <=2 lanes/bank.
__global__ __launch_bounds__(512, 2) void gemm_bt(const float* __restrict__ xg,
                                                  const __bf16* __restrict__ Sg,
                                                  const __bf16* __restrict__ B,
                                                  __bf16* __restrict__ Cp) {
    __shared__ __attribute__((aligned(16))) __bf16 As[2 * ATILEA];
    __shared__ __attribute__((aligned(16))) __bf16 Bs[2 * ATILEB];

    const int tid  = threadIdx.x;
    const int wave = tid >> 6, lane = tid & 63;
    const int q    = lane >> 4, r16 = lane & 15;
    const int m0 = blockIdx.x * 256, n0 = blockIdx.y * 256, k0 = blockIdx.z * KS;
    const int wm = wave >> 2, wn = wave & 3;     // 2x4 waves; per-wave 128x64 out

    // B gll16 staging map: chunk g: row=g>>3, pos=g&7, source col
    // c = pos ^ ((row>>1)&7). Thread t covers chunks t,512+t,1024+t,1536+t.
    const int sr = tid >> 3;                           // 0..63
    const int sc = (tid & 7) ^ ((tid >> 4) & 7);       // de-swizzled source col
    const __bf16* gB0 = B + (size_t)(n0 + sr) * KT       + k0 + sc * 8;
    const __bf16* gB1 = B + (size_t)(n0 + 64  + sr) * KT + k0 + sc * 8;
    const __bf16* gB2 = B + (size_t)(n0 + 128 + sr) * KT + k0 + sc * 8;
    const __bf16* gB3 = B + (size_t)(n0 + 192 + sr) * KT + k0 + sc * 8;
    // silu reg-stage source (no XOR — padded A dest is direct-placement)
    const int scA = tid & 7;
    const __bf16* gSa0 = Sg + (size_t)(m0 + sr) * 512       + scA * 8;
    const __bf16* gSa1 = Sg + (size_t)(m0 + 64  + sr) * 512 + scA * 8;
    const __bf16* gSa2 = Sg + (size_t)(m0 + 128 + sr) * 512 + scA * 8;
    const __bf16* gSa3 = Sg + (size_t)(m0 + 192 + sr) * 512 + scA * 8;

    // basis staging map: thread t owns row pr = t>>1, x-col pair pha = t&1.
    const int pr  = tid >> 1, pha = tid & 1;
    const int wb0 = pr * AP;                           // row base, elems
    const float* xrow = xg + (size_t)(m0 + pr) * 512 + 2 * pha;  // NO k0

    f32x4 acc[8][4] = {};

    // A read offsets (padded, no XOR): chunk q (ks0) / 4+q (ks1) directly.
    const int qx0 = q * 8;
    const int qx1 = (4 + q) * 8;
    const int aro = (wm * 128 + r16) * AP;
    // B read offsets (XOR de-swizzle, unchanged)
    const int swl = (r16 >> 1) & 7;
    const int bx0 = ((q)     ^ swl) * 8;
    const int bx1 = ((4 + q) ^ swl) * 8;
    const int bro = (wn * 64 + r16) * 64;

    // compute basis for one x value into row pr, chunks 2ci / 2ci+1 (padded)
    auto wb_col = [&](float xc, int ci, int so) {
        const float zb = 3.75f * xc + 7.5f;      // z_j = zb - j
        bf16x8 lo, hi;
#pragma unroll
        for (int j = 0; j < 8; ++j)  { float z = zb - (float)j;  lo[j]     = (__bf16)__expf(-z * z); }
#pragma unroll
        for (int j = 8; j < 16; ++j) { float z = zb - (float)j;  hi[j - 8] = (__bf16)__expf(-z * z); }
        *(bf16x8*)(As + so + wb0 + (2 * ci)     * 8) = lo;
        *(bf16x8*)(As + so + wb0 + (2 * ci + 1) * 8) = hi;
    };

    // prologue: B(0) via gll16 (gB* already at k0); A(0) basis (tile 0 is
    // basis for all z: max k0 = 7616 < 8192) computed from x into slot 0.
    float2 xv0 = *(const float2*)(xrow + (k0 >> 4));
    gll16(gB0, &Bs[(size_t)tid * 8]);
    gll16(gB1, &Bs[(size_t)(512 + tid) * 8]);
    gll16(gB2, &Bs[(size_t)(1024 + tid) * 8]);
    gll16(gB3, &Bs[(size_t)(1536 + tid) * 8]);
    wb_col(xv0.x, 2 * pha,     0);
    wb_col(xv0.y, 2 * pha + 1, 0);
    __syncthreads();

    bf16x8 a[4], b[4];
    bf16x8 sv0, sv1, sv2, sv3;                   // silu stage (z=7 tiles)
    float2 xn = xv0;                             // next-tile x (basis path)
    for (int u = 0; u < NT2; ++u) {
        const int s    = u & 1;
        const int cboA = s * ATILEA;             // compute slots (tile u)
        const int cboB = s * ATILEB;
        const int so1A = (s ^ 1) * ATILEA;       // staging slots (tile u+1)
        const int so1B = (s ^ 1) * ATILEB;
        const int k1   = (u + 1) * 64;           // tile-local (gB*: k0 baked in)
        const int kn   = k0 + k1;                // GLOBAL k-base of tile u+1
        const bool nb  = kn < 8192;              // next tile is basis?
        const int kk   = kn - 8192;              // silu col base (when !nb)
        // Tail (u+1==NT2): basis z<7 reads valid x cols; silu z=7 reads
        // <=512 elems past Asilu rows -> lands in Bm (mapped, unused);
        // B reads <=128 B past Bm -> lands in Cp (mapped, unused).

        // -------- phase 0: ks=0, mi 0..3 (8 ds_read) --------
#pragma unroll
        for (int mi = 0; mi < 4; ++mi) a[mi] = *(const bf16x8*)(As + cboA + aro + mi * 16 * AP + qx0);
#pragma unroll
        for (int ni = 0; ni < 4; ++ni) b[ni] = *(const bf16x8*)(Bs + cboB + bro + ni * 1024 + bx0);
        gll16(gB0 + k1, &Bs[(size_t)(so1B + tid * 8)]);
        gll16(gB1 + k1, &Bs[(size_t)(so1B + (512 + tid) * 8)]);
        if (nb) xn = *(const float2*)(xrow + (kn >> 4));
        __builtin_amdgcn_s_setprio(1);
#pragma unroll
        for (int mi = 0; mi < 4; ++mi)
#pragma unroll
            for (int ni = 0; ni < 4; ++ni)
                acc[mi][ni] = __builtin_amdgcn_mfma_f32_16x16x32_bf16(a[mi], b[ni], acc[mi][ni], 0, 0, 0);
        __builtin_amdgcn_s_setprio(0);
        __builtin_amdgcn_s_barrier();

        // -------- phase 1: ks=0, mi 4..7 (4 ds_read, reuse b) --------
#pragma unroll
        for (int mi = 0; mi < 4; ++mi) a[mi] = *(const bf16x8*)(As + cboA + aro + (4 + mi) * 16 * AP + qx0);
        gll16(gB2 + k1, &Bs[(size_t)(so1B + (1024 + tid) * 8)]);
        gll16(gB3 + k1, &Bs[(size_t)(so1B + (1536 + tid) * 8)]);
        __builtin_amdgcn_s_setprio(1);
#pragma unroll
        for (int mi = 0; mi < 4; ++mi)
#pragma unroll
            for (int ni = 0; ni < 4; ++ni)
                acc[4 + mi][ni] = __builtin_amdgcn_mfma_f32_16x16x32_bf16(a[mi], b[ni], acc[4 + mi][ni], 0, 0, 0);
        __builtin_amdgcn_s_setprio(0);
        __builtin_amdgcn_s_barrier();

        // -------- phase 2: ks=1, mi 0..3 (8 ds_read) + A-stage part 1 -----
#pragma unroll
        for (int mi = 0; mi < 4; ++mi) a[mi] = *(const bf16x8*)(As + cboA + aro + mi * 16 * AP + qx1);
#pragma unroll
        for (int ni = 0; ni < 4; ++ni) b[ni] = *(const bf16x8*)(Bs + cboB + bro + ni * 1024 + bx1);
        if (nb) {
            wb_col(xn.x, 2 * pha, so1A);         // basis x-col e=0: 16 exp + 2 writes
        } else {
            sv0 = *(const bf16x8*)(gSa0 + kk);   // silu reg-loads (z=7)
            sv1 = *(const bf16x8*)(gSa1 + kk);
            sv2 = *(const bf16x8*)(gSa2 + kk);
            sv3 = *(const bf16x8*)(gSa3 + kk);
        }
        __builtin_amdgcn_s_setprio(1);
#pragma unroll
        for (int mi = 0; mi < 4; ++mi)
#pragma unroll
            for (int ni = 0; ni < 4; ++ni)
                acc[mi][ni] = __builtin_amdgcn_mfma_f32_16x16x32_bf16(a[mi], b[ni], acc[mi][ni], 0, 0, 0);
        __builtin_amdgcn_s_setprio(0);
        __builtin_amdgcn_s_barrier();

        // -------- phase 3: ks=1, mi 4..7 (4 ds_read) + A-stage part 2 -----
#pragma unroll
        for (int mi = 0; mi < 4; ++mi) a[mi] = *(const bf16x8*)(As + cboA + aro + (4 + mi) * 16 * AP + qx1);
        if (nb) {
            wb_col(xn.y, 2 * pha + 1, so1A);     // basis x-col e=1
        } else {
            *(bf16x8*)(As + so1A + (sr)       * AP + scA * 8) = sv0;
            *(bf16x8*)(As + so1A + (sr + 64)  * AP + scA * 8) = sv1;
            *(bf16x8*)(As + so1A + (sr + 128) * AP + scA * 8) = sv2;
            *(bf16x8*)(As + so1A + (sr + 192) * AP + scA * 8) = sv3;
        }
        __builtin_amdgcn_s_setprio(1);
#pragma unroll
        for (int mi = 0; mi < 4; ++mi)
#pragma unroll
            for (int ni = 0; ni < 4; ++ni)
                acc[4 + mi][ni] = __builtin_amdgcn_mfma_f32_16x16x32_bf16(a[mi], b[ni], acc[4 + mi][ni], 0, 0, 0);
        __builtin_amdgcn_s_setprio(0);
        // tile end: compiler-understood full drain + barrier. Publishes the
        // A ds_writes and drains the B DMA (issued 2-3 phases ago).
        __syncthreads();
    }

    // epilogue: C/D layout col=lane&15, row=(lane>>4)*4+reg; bf16 partials
    __bf16* Cb = Cp + (size_t)blockIdx.z * CPE;
#pragma unroll
    for (int mi = 0; mi < 8; ++mi) {
        const int row = m0 + wm * 128 + mi * 16 + q * 4;
#pragma unroll
        for (int ni = 0; ni < 4; ++ni) {
            const int col = n0 + wn * 64 + ni * 16 + r16;
#pragma unroll
            for (int r = 0; r < 4; ++r)
                Cb[(size_t)(row + r) * 512 + col] = (__bf16)acc[mi][ni][r];
        }
    }
}

// ---- kernel 3: sum 8 bf16 partials + LayerNorm, one wave per row ----------
__global__ void ln_kernel(const __bf16* __restrict__ Cp, const float* __restrict__ gamma,
                          const float* __restrict__ beta, float* __restrict__ out) {
    const int tid  = threadIdx.x;
    const int wave = tid >> 6, lane = tid & 63;
    const int row  = blockIdx.x * 4 + wave;
    const size_t base = (size_t)row * 512 + lane * 8;   // 8 contiguous cols/lane

    float v[8] = {};
    float s = 0.f, s2 = 0.f;
#pragma unroll
    for (int z = 0; z < SPLITS; ++z) {
        bf16x8 p = *(const bf16x8*)(Cp + (size_t)z * CPE + base);
#pragma unroll
        for (int j = 0; j < 8; ++j) v[j] += (float)p[j];
    }
#pragma unroll
    for (int j = 0; j < 8; ++j) { s += v[j]; s2 += v[j] * v[j]; }
#pragma unroll
    for (int m = 32; m >= 1; m >>= 1) {
        s  += __shfl_xor(s, m);
        s2 += __shfl_xor(s2, m);
    }
    const float mean = s * (1.0f / 512.0f);
    const float var  = s2 * (1.0f / 512.0f) - mean * mean;
    const float rs   = rsqrtf(var + 1e-5f);
    float4 o0, o1;
    const float4 g0 = *(const float4*)&gamma[lane * 8];
    const float4 g1 = *(const float4*)&gamma[lane * 8 + 4];
    const float4 b0 = *(const float4*)&beta[lane * 8];
    const float4 b1 = *(const float4*)&beta[lane * 8 + 4];
    o0.x = (v[0] - mean) * rs * g0.x + b0.x;
    o0.y = (v[1] - mean) * rs * g0.y + b0.y;
    o0.z = (v[2] - mean) * rs * g0.z + b0.z;
    o0.w = (v[3] - mean) * rs * g0.w + b0.w;
    o1.x = (v[4] - mean) * rs * g1.x + b1.x;
    o1.y = (v[5] - mean) * rs * g1.y + b1.y;
    o1.z = (v[6] - mean) * rs * g1.z + b1.z;
    o1.w = (v[7] - mean) * rs * g1.w + b1.w;
    *(float4*)&out[base]     = o0;
    *(float4*)&out[base + 4] = o1;
}

extern "C" void kernel_launch(void* const* d_in, const int* in_sizes, int n_in,
                              void* d_out, int out_size, void* d_ws, size_t ws_size,
                              hipStream_t stream) {
    const float* x     = (const float*)d_in[0];
    const float* W     = (const float*)d_in[1];
    const float* Wb    = (const float*)d_in[2];
    const float* gamma = (const float*)d_in[3];
    const float* beta  = (const float*)d_in[4];
    float* out = (float*)d_out;

    char* ws = (char*)d_ws;
    __bf16* Asilu = (__bf16*)ws;                     //  4,194,304 B
    __bf16* Bm    = (__bf16*)(ws + 4194304);         //  8,912,896 B
    __bf16* Cp    = (__bf16*)(ws + 13107200);        // 33,554,432 B

    prep_AB<<<1024 + 4352, 256, 0, stream>>>(x, W, Wb, Asilu, Bm);
    dim3 g(16, 2, SPLITS);
    gemm_bt<<<g, 512, 0, stream>>>(x, Asilu, Bm, Cp);
    ln_kernel<<<1024, 256, 0, stream>>>(Cp, gamma, beta, out);
}

// Round 9
// 133.518 us; speedup vs baseline: 1.0031x; 1.0031x over previous
//
#include <hip/hip_runtime.h>
#include <hip/hip_bf16.h>

// KAN layer: out = einsum('bik,jik->bj', rbf(x), W) + silu(x)@Wb^T, then LN.
// GEMM view: C[4096,512] = A[4096,8704] * B[512,8704]^T in bf16 MFMA, where
// A = [rbf basis(x) | silu(x)], basis computed in-GEMM (not materialized).
//
// R8 post-mortem: conflicts DOUBLED with padded rows (2.23M = 16 cyc/write;
// R7 XOR = 8 cyc/write). Both static bank models failed -> stop modeling.
// Empirical anchor: R4's zero-conflict staging wrote LDS ONLY via gll16,
// whose dest pattern is lane-LINEAR (base + tid*16B). R9: basis ds_writes
// use the EXACT same linear dest slots {t,512+t,1024+t,1536+t}*16B; the
// XOR permutation moves to the COMPUTATION side: thread t computes the
// basis values belonging at its slot (row g>>3, src chunk c = sc =
// (t&7)^((t>>4)&7), x-col (kn>>4)+(sc>>1), j-half 8*(sc&1)). 4 scalar x
// loads/thread/tile (ph0), 32 exps split ph2/ph3, 4 linear b128 stores.
// A layout/read = R7's XOR [256][64] (= R4-proven). Silu via gll16 (R7).
//
// d_ws layout (uses 46.7 MB of the 113.7 MB ws):
//   Asilu bf16 [4096][512]   @ 0          ( 4,194,304 B)  silu(x)
//   Bm    bf16 [512][8704]   @ 4194304    ( 8,912,896 B)  Bm = [W | Wb]
//   Cp    bf16 [8][4096][512]@ 13107200   (33,554,432 B)  split-K partials

typedef __bf16 bf16x8 __attribute__((ext_vector_type(8)));
typedef __bf16 bf16x4 __attribute__((ext_vector_type(4)));
typedef float  f32x4  __attribute__((ext_vector_type(4)));

#define KT 8704            // total K = 512*16 + 512
#define SPLITS 8
#define KS (KT / SPLITS)   // 1088 per z-block
#define NT2 (KS / 64)      // 17 K-tiles of BK=64
#define CPE (4096 * 512)   // elements per partial
#define ATILE (256 * 64)   // one tile slot per matrix: 256 rows x 64 k, elems

__device__ __forceinline__ void gll16(const __bf16* g, __bf16* l) {
    __builtin_amdgcn_global_load_lds(
        (const __attribute__((address_space(1))) void*)g,
        (__attribute__((address_space(3))) void*)l, 16, 0, 0);
}

// ---- kernel 1: Asilu = silu(x) (bf16), Bm = [W | Wb] (bf16) ---------------
__global__ void prep_AB(const float* __restrict__ x, const float* __restrict__ W,
                        const float* __restrict__ Wb, __bf16* __restrict__ Asilu,
                        __bf16* __restrict__ B) {
    if (blockIdx.x < 1024) {                     // silu: 8 elems/thread
        int t = blockIdx.x * 256 + threadIdx.x;  // 0 .. 262143
        int e = t * 8;
        float4 v0 = *(const float4*)&x[e];
        float4 v1 = *(const float4*)&x[e + 4];
        float vs[8] = {v0.x, v0.y, v0.z, v0.w, v1.x, v1.y, v1.z, v1.w};
        bf16x8 o;
#pragma unroll
        for (int j = 0; j < 8; ++j) o[j] = (__bf16)(vs[j] / (1.0f + __expf(-vs[j])));
        *(bf16x8*)&Asilu[e] = o;
    } else {                                     // B-part: cast W|Wb, 4 elems/thread
        int t = (blockIdx.x - 1024) * 256 + threadIdx.x;  // 0 .. 512*2176
        int j = t / 2176;
        int c = (t - j * 2176) * 4;
        float4 v;
        if (c < 8192) v = *(const float4*)&W[(size_t)j * 8192 + c];
        else          v = *(const float4*)&Wb[(size_t)j * 512 + (c - 8192)];
        bf16x4 o;
        o[0] = (__bf16)v.x; o[1] = (__bf16)v.y; o[2] = (__bf16)v.z; o[3] = (__bf16)v.w;
        *(bf16x4*)&B[(size_t)j * KT + c] = o;
    }
}

// ---- kernel 2: fused split-K GEMM, 256x256 tile, 8 waves, BK=64, 4-phase --
// Per K-tile: ph0 {ds_read a0-3,b ks0; 2 gll16 B(u+1); 4 x-loads if nb} ->
//             ph1 {a4-7 ks0; 2 gll16 B(u+1); 2 silu gll16 if !nb} ->
//             ph2 {a0-3,b ks1; 2 basis stores if nb / 2 silu gll16 if !nb} ->
//             ph3 {a4-7 ks1; 2 basis stores if nb} -> __syncthreads().
// setprio(1) around each 16-MFMA cluster. All staging -> slot^1 (last read
// at tile u-1, drained by its __syncthreads -> WAR-safe). Tile-end
// __syncthreads publishes basis ds_writes and drains the B/silu DMA.
//
// LDS chunk layout (both As and Bs, = R4-proven): per slot, 2048 chunks of
// 16B; chunk index g holds source (row = g>>3, src col c = (g&7)^((row>>1)
// &7)). Reads de-swizzle with (q or 4+q) ^ ((r16>>1)&7). ALL writes (DMA
// and basis stores) are lane-linear: thread t -> chunks t,512+t,1024+t,
// 1536+t (rows sr, sr+64, sr+128, sr+192; same c since 64>>1 === 0 mod 8).
__global__ __launch_bounds__(512, 2) void gemm_bt(const float* __restrict__ xg,
                                                  const __bf16* __restrict__ Sg,
                                                  const __bf16* __restrict__ B,
                                                  __bf16* __restrict__ Cp) {
    __shared__ __attribute__((aligned(16))) __bf16 As[2 * ATILE];
    __shared__ __attribute__((aligned(16))) __bf16 Bs[2 * ATILE];

    const int tid  = threadIdx.x;
    const int wave = tid >> 6, lane = tid & 63;
    const int q    = lane >> 4, r16 = lane & 15;
    const int m0 = blockIdx.x * 256, n0 = blockIdx.y * 256, k0 = blockIdx.z * KS;
    const int wm = wave >> 2, wn = wave & 3;     // 2x4 waves; per-wave 128x64 out

    const int sr = tid >> 3;                           // 0..63
    const int sc = (tid & 7) ^ ((tid >> 4) & 7);       // de-swizzled source col
    const __bf16* gB0 = B + (size_t)(n0 + sr) * KT       + k0 + sc * 8;
    const __bf16* gB1 = B + (size_t)(n0 + 64  + sr) * KT + k0 + sc * 8;
    const __bf16* gB2 = B + (size_t)(n0 + 128 + sr) * KT + k0 + sc * 8;
    const __bf16* gB3 = B + (size_t)(n0 + 192 + sr) * KT + k0 + sc * 8;
    // silu gll16 source (row stride 512; per-tile kk added later; NO k0)
    const __bf16* gS0 = Sg + (size_t)(m0 + sr) * 512       + sc * 8;
    const __bf16* gS1 = Sg + (size_t)(m0 + 64  + sr) * 512 + sc * 8;
    const __bf16* gS2 = Sg + (size_t)(m0 + 128 + sr) * 512 + sc * 8;
    const __bf16* gS3 = Sg + (size_t)(m0 + 192 + sr) * 512 + sc * 8;
    // basis x sources: thread t needs x[m0 + sr + {0,64,128,192}][xcol],
    // xcol = (kbase>>4) + (sc>>1); j-half = 8*(sc&1).
    const float* xp0 = xg + (size_t)(m0 + sr) * 512       + (sc >> 1);
    const float* xp1 = xg + (size_t)(m0 + 64  + sr) * 512 + (sc >> 1);
    const float* xp2 = xg + (size_t)(m0 + 128 + sr) * 512 + (sc >> 1);
    const float* xp3 = xg + (size_t)(m0 + 192 + sr) * 512 + (sc >> 1);
    const float j0f  = (float)(8 * (sc & 1));

    f32x4 acc[8][4] = {};

    // read offsets (XOR de-swizzle, = R4/R7)
    const int swl = (r16 >> 1) & 7;
    const int qx0 = ((q)     ^ swl) * 8;         // ks=0 chunk
    const int qx1 = ((4 + q) ^ swl) * 8;         // ks=1 chunk
    const int aro = (wm * 128 + r16) * 64;
    const int bro = (wn * 64  + r16) * 64;

    // 8 basis values (j = j0..j0+7) for one x value
    auto basis8 = [&](float xv) -> bf16x8 {
        const float zc = 3.75f * xv + 7.5f - j0f;    // z_j = zc - d
        bf16x8 o;
#pragma unroll
        for (int d = 0; d < 8; ++d) { float z = zc - (float)d; o[d] = (__bf16)__expf(-z * z); }
        return o;
    };

    // prologue: B(0) via gll16 (gB* already at k0); A(0) basis (tile 0 is
    // basis for all z: max k0 = 7616 < 8192), lane-linear stores into slot 0.
    {
        const int xo = k0 >> 4;
        float x0 = xp0[xo], x1 = xp1[xo], x2 = xp2[xo], x3 = xp3[xo];
        gll16(gB0, &Bs[(size_t)tid * 8]);
        gll16(gB1, &Bs[(size_t)(512 + tid) * 8]);
        gll16(gB2, &Bs[(size_t)(1024 + tid) * 8]);
        gll16(gB3, &Bs[(size_t)(1536 + tid) * 8]);
        *(bf16x8*)(As + (size_t)tid * 8)          = basis8(x0);
        *(bf16x8*)(As + (size_t)(512 + tid) * 8)  = basis8(x1);
        *(bf16x8*)(As + (size_t)(1024 + tid) * 8) = basis8(x2);
        *(bf16x8*)(As + (size_t)(1536 + tid) * 8) = basis8(x3);
    }
    __syncthreads();

    bf16x8 a[4], b[4];
    for (int u = 0; u < NT2; ++u) {
        const int s   = u & 1;
        const int cbo = s * ATILE;               // compute slot (tile u)
        const int so1 = (s ^ 1) * ATILE;         // staging slot (tile u+1)
        const int k1  = (u + 1) * 64;            // tile-local (gB*: k0 baked in)
        const int kn  = k0 + k1;                 // GLOBAL k-base of tile u+1
        const bool nb = kn < 8192;               // next tile is basis?
        const int kk  = kn - 8192;               // silu col base (when !nb)
        float x0, x1, x2, x3;
        // Tail (u+1==NT2): basis z<7 reads valid x cols (<=479); silu z=7
        // reads <=512 elems past Asilu rows -> lands in Bm (mapped, unused);
        // B reads <=128 B past the slice -> mapped, never consumed.

        // -------- phase 0: ks=0, mi 0..3 (8 ds_read) --------
#pragma unroll
        for (int mi = 0; mi < 4; ++mi) a[mi] = *(const bf16x8*)(As + cbo + aro + mi * 1024 + qx0);
#pragma unroll
        for (int ni = 0; ni < 4; ++ni) b[ni] = *(const bf16x8*)(Bs + cbo + bro + ni * 1024 + qx0);
        gll16(gB0 + k1, &Bs[(size_t)(so1 + tid * 8)]);
        gll16(gB1 + k1, &Bs[(size_t)(so1 + (512 + tid) * 8)]);
        if (nb) {
            const int xo = kn >> 4;
            x0 = xp0[xo]; x1 = xp1[xo]; x2 = xp2[xo]; x3 = xp3[xo];
        }
        __builtin_amdgcn_s_setprio(1);
#pragma unroll
        for (int mi = 0; mi < 4; ++mi)
#pragma unroll
            for (int ni = 0; ni < 4; ++ni)
                acc[mi][ni] = __builtin_amdgcn_mfma_f32_16x16x32_bf16(a[mi], b[ni], acc[mi][ni], 0, 0, 0);
        __builtin_amdgcn_s_setprio(0);
        __builtin_amdgcn_s_barrier();

        // -------- phase 1: ks=0, mi 4..7 (4 ds_read, reuse b) --------
#pragma unroll
        for (int mi = 0; mi < 4; ++mi) a[mi] = *(const bf16x8*)(As + cbo + aro + (4 + mi) * 1024 + qx0);
        gll16(gB2 + k1, &Bs[(size_t)(so1 + (1024 + tid) * 8)]);
        gll16(gB3 + k1, &Bs[(size_t)(so1 + (1536 + tid) * 8)]);
        if (!nb) {
            gll16(gS0 + kk, &As[(size_t)(so1 + tid * 8)]);
            gll16(gS1 + kk, &As[(size_t)(so1 + (512 + tid) * 8)]);
        }
        __builtin_amdgcn_s_setprio(1);
#pragma unroll
        for (int mi = 0; mi < 4; ++mi)
#pragma unroll
            for (int ni = 0; ni < 4; ++ni)
                acc[4 + mi][ni] = __builtin_amdgcn_mfma_f32_16x16x32_bf16(a[mi], b[ni], acc[4 + mi][ni], 0, 0, 0);
        __builtin_amdgcn_s_setprio(0);
        __builtin_amdgcn_s_barrier();

        // -------- phase 2: ks=1, mi 0..3 (8 ds_read) + A-stage part 1 -----
#pragma unroll
        for (int mi = 0; mi < 4; ++mi) a[mi] = *(const bf16x8*)(As + cbo + aro + mi * 1024 + qx1);
#pragma unroll
        for (int ni = 0; ni < 4; ++ni) b[ni] = *(const bf16x8*)(Bs + cbo + bro + ni * 1024 + qx1);
        if (nb) {                                // lane-linear stores (= DMA pattern)
            *(bf16x8*)(As + so1 + (size_t)tid * 8)          = basis8(x0);
            *(bf16x8*)(As + so1 + (size_t)(1024 + tid) * 8) = basis8(x2);
        } else {
            gll16(gS2 + kk, &As[(size_t)(so1 + (1024 + tid) * 8)]);
            gll16(gS3 + kk, &As[(size_t)(so1 + (1536 + tid) * 8)]);
        }
        __builtin_amdgcn_s_setprio(1);
#pragma unroll
        for (int mi = 0; mi < 4; ++mi)
#pragma unroll
            for (int ni = 0; ni < 4; ++ni)
                acc[mi][ni] = __builtin_amdgcn_mfma_f32_16x16x32_bf16(a[mi], b[ni], acc[mi][ni], 0, 0, 0);
        __builtin_amdgcn_s_setprio(0);
        __builtin_amdgcn_s_barrier();

        // -------- phase 3: ks=1, mi 4..7 (4 ds_read) + A-stage part 2 -----
#pragma unroll
        for (int mi = 0; mi < 4; ++mi) a[mi] = *(const bf16x8*)(As + cbo + aro + (4 + mi) * 1024 + qx1);
        if (nb) {
            *(bf16x8*)(As + so1 + (size_t)(512 + tid) * 8)  = basis8(x1);
            *(bf16x8*)(As + so1 + (size_t)(1536 + tid) * 8) = basis8(x3);
        }
        __builtin_amdgcn_s_setprio(1);
#pragma unroll
        for (int mi = 0; mi < 4; ++mi)
#pragma unroll
            for (int ni = 0; ni < 4; ++ni)
                acc[4 + mi][ni] = __builtin_amdgcn_mfma_f32_16x16x32_bf16(a[mi], b[ni], acc[4 + mi][ni], 0, 0, 0);
        __builtin_amdgcn_s_setprio(0);
        // tile end: compiler-understood full drain + barrier. Publishes the
        // basis ds_writes and drains the B/silu DMA (issued 1-3 phases ago).
        __syncthreads();
    }

    // epilogue: C/D layout col=lane&15, row=(lane>>4)*4+reg; bf16 partials
    __bf16* Cb = Cp + (size_t)blockIdx.z * CPE;
#pragma unroll
    for (int mi = 0; mi < 8; ++mi) {
        const int row = m0 + wm * 128 + mi * 16 + q * 4;
#pragma unroll
        for (int ni = 0; ni < 4; ++ni) {
            const int col = n0 + wn * 64 + ni * 16 + r16;
#pragma unroll
            for (int r = 0; r < 4; ++r)
                Cb[(size_t)(row + r) * 512 + col] = (__bf16)acc[mi][ni][r];
        }
    }
}

// ---- kernel 3: sum 8 bf16 partials + LayerNorm, one wave per row ----------
__global__ void ln_kernel(const __bf16* __restrict__ Cp, const float* __restrict__ gamma,
                          const float* __restrict__ beta, float* __restrict__ out) {
    const int tid  = threadIdx.x;
    const int wave = tid >> 6, lane = tid & 63;
    const int row  = blockIdx.x * 4 + wave;
    const size_t base = (size_t)row * 512 + lane * 8;   // 8 contiguous cols/lane

    float v[8] = {};
    float s = 0.f, s2 = 0.f;
#pragma unroll
    for (int z = 0; z < SPLITS; ++z) {
        bf16x8 p = *(const bf16x8*)(Cp + (size_t)z * CPE + base);
#pragma unroll
        for (int j = 0; j < 8; ++j) v[j] += (float)p[j];
    }
#pragma unroll
    for (int j = 0; j < 8; ++j) { s += v[j]; s2 += v[j] * v[j]; }
#pragma unroll
    for (int m = 32; m >= 1; m >>= 1) {
        s  += __shfl_xor(s, m);
        s2 += __shfl_xor(s2, m);
    }
    const float mean = s * (1.0f / 512.0f);
    const float var  = s2 * (1.0f / 512.0f) - mean * mean;
    const float rs   = rsqrtf(var + 1e-5f);
    float4 o0, o1;
    const float4 g0 = *(const float4*)&gamma[lane * 8];
    const float4 g1 = *(const float4*)&gamma[lane * 8 + 4];
    const float4 b0 = *(const float4*)&beta[lane * 8];
    const float4 b1 = *(const float4*)&beta[lane * 8 + 4];
    o0.x = (v[0] - mean) * rs * g0.x + b0.x;
    o0.y = (v[1] - mean) * rs * g0.y + b0.y;
    o0.z = (v[2] - mean) * rs * g0.z + b0.z;
    o0.w = (v[3] - mean) * rs * g0.w + b0.w;
    o1.x = (v[4] - mean) * rs * g1.x + b1.x;
    o1.y = (v[5] - mean) * rs * g1.y + b1.y;
    o1.z = (v[6] - mean) * rs * g1.z + b1.z;
    o1.w = (v[7] - mean) * rs * g1.w + b1.w;
    *(float4*)&out[base]     = o0;
    *(float4*)&out[base + 4] = o1;
}

extern "C" void kernel_launch(void* const* d_in, const int* in_sizes, int n_in,
                              void* d_out, int out_size, void* d_ws, size_t ws_size,
                              hipStream_t stream) {
    const float* x     = (const float*)d_in[0];
    const float* W     = (const float*)d_in[1];
    const float* Wb    = (const float*)d_in[2];
    const float* gamma = (const float*)d_in[3];
    const float* beta  = (const float*)d_in[4];
    float* out = (float*)d_out;

    char* ws = (char*)d_ws;
    __bf16* Asilu = (__bf16*)ws;                     //  4,194,304 B
    __bf16* Bm    = (__bf16*)(ws + 4194304);         //  8,912,896 B
    __bf16* Cp    = (__bf16*)(ws + 13107200);        // 33,554,432 B

    prep_AB<<<1024 + 4352, 256, 0, stream>>>(x, W, Wb, Asilu, Bm);
    dim3 g(16, 2, SPLITS);
    gemm_bt<<<g, 512, 0, stream>>>(x, Asilu, Bm, Cp);
    ln_kernel<<<1024, 256, 0, stream>>>(Cp, gamma, beta, out);
}

// Round 10
// 130.388 us; speedup vs baseline: 1.0272x; 1.0240x over previous
//
#include <hip/hip_runtime.h>
#include <hip/hip_bf16.h>

// KAN layer: out = einsum('bik,jik->bj', rbf(x), W) + silu(x)@Wb^T, then LN.
// GEMM view: C[4096,512] = A[4096,8704] * B[512,8704]^T in bf16 MFMA, where
// A = [rbf basis(x) | silu(x)], basis computed in-GEMM (not materialized).
//
// R9 post-mortem: lane-linear basis stores -> conflicts 2.23M -> 0, but
// timing unchanged (~52us). Conflicts were a symptom, not the cost. All
// pipes <30% busy; per-tile time 7.3K cyc vs ~1.5K content. Remaining
// suspect: sync granularity — 5 barriers/tile with only 2 waves/SIMD means
// every phase pays convergence + straggler jitter. R10: merge 4 phases ->
// 2 (P0 = all ks0, P1 = all ks1): 12 ds_read + 32 MFMA per phase, ALL DMA
// issued in P0 (tile-end drain sees >=1-phase-old loads). x loads for the
// basis are software-pipelined one tile ahead (issue P0 of tile u for tile
// u+1's stores at tile u+1; commit at P1 end) to keep load->use distance.
// Mapping (lane-linear writes, XOR reads) byte-identical to passing R9.
//
// d_ws layout (uses 46.7 MB of the 113.7 MB ws):
//   Asilu bf16 [4096][512]   @ 0          ( 4,194,304 B)  silu(x)
//   Bm    bf16 [512][8704]   @ 4194304    ( 8,912,896 B)  Bm = [W | Wb]
//   Cp    bf16 [8][4096][512]@ 13107200   (33,554,432 B)  split-K partials

typedef __bf16 bf16x8 __attribute__((ext_vector_type(8)));
typedef __bf16 bf16x4 __attribute__((ext_vector_type(4)));
typedef float  f32x4  __attribute__((ext_vector_type(4)));

#define KT 8704            // total K = 512*16 + 512
#define SPLITS 8
#define KS (KT / SPLITS)   // 1088 per z-block
#define NT2 (KS / 64)      // 17 K-tiles of BK=64
#define CPE (4096 * 512)   // elements per partial
#define ATILE (256 * 64)   // one tile slot per matrix: 256 rows x 64 k, elems

__device__ __forceinline__ void gll16(const __bf16* g, __bf16* l) {
    __builtin_amdgcn_global_load_lds(
        (const __attribute__((address_space(1))) void*)g,
        (__attribute__((address_space(3))) void*)l, 16, 0, 0);
}

// ---- kernel 1: Asilu = silu(x) (bf16), Bm = [W | Wb] (bf16) ---------------
__global__ void prep_AB(const float* __restrict__ x, const float* __restrict__ W,
                        const float* __restrict__ Wb, __bf16* __restrict__ Asilu,
                        __bf16* __restrict__ B) {
    if (blockIdx.x < 1024) {                     // silu: 8 elems/thread
        int t = blockIdx.x * 256 + threadIdx.x;  // 0 .. 262143
        int e = t * 8;
        float4 v0 = *(const float4*)&x[e];
        float4 v1 = *(const float4*)&x[e + 4];
        float vs[8] = {v0.x, v0.y, v0.z, v0.w, v1.x, v1.y, v1.z, v1.w};
        bf16x8 o;
#pragma unroll
        for (int j = 0; j < 8; ++j) o[j] = (__bf16)(vs[j] / (1.0f + __expf(-vs[j])));
        *(bf16x8*)&Asilu[e] = o;
    } else {                                     // B-part: cast W|Wb, 4 elems/thread
        int t = (blockIdx.x - 1024) * 256 + threadIdx.x;  // 0 .. 512*2176
        int j = t / 2176;
        int c = (t - j * 2176) * 4;
        float4 v;
        if (c < 8192) v = *(const float4*)&W[(size_t)j * 8192 + c];
        else          v = *(const float4*)&Wb[(size_t)j * 512 + (c - 8192)];
        bf16x4 o;
        o[0] = (__bf16)v.x; o[1] = (__bf16)v.y; o[2] = (__bf16)v.z; o[3] = (__bf16)v.w;
        *(bf16x4*)&B[(size_t)j * KT + c] = o;
    }
}

// ---- kernel 2: fused split-K GEMM, 256x256 tile, 8 waves, BK=64, 2-phase --
// Per K-tile u:
//  P0 (ks=0): 12 ds_read (a0-7, b0-3) | 4 gll16 B(u+1) | if nb: 2 basis
//     stores (xA,xC) + issue 4 x loads (tile u+2) ; else 4 silu gll16
//     -> setprio 32 MFMA -> s_barrier
//  P1 (ks=1): 12 ds_read | if nb: 2 basis stores (xB,xD)
//     -> setprio 32 MFMA -> commit x regs -> __syncthreads
// All staging targets slot^1 (last read in tile u-1's P1, drained by its
// __syncthreads -> WAR-safe). Tile-end __syncthreads publishes basis
// ds_writes and drains the DMA (all issued in P0, >=1 phase old).
//
// LDS chunk layout (= R9-proven): per slot, 2048 chunks of 16B; chunk g
// holds source (row = g>>3, src col c = (g&7)^((row>>1)&7)). Reads
// de-swizzle with (q or 4+q)^((r16>>1)&7). ALL writes lane-linear:
// thread t -> chunks t,512+t,1024+t,1536+t (zero-conflict, R9-measured).
__global__ __launch_bounds__(512, 2) void gemm_bt(const float* __restrict__ xg,
                                                  const __bf16* __restrict__ Sg,
                                                  const __bf16* __restrict__ B,
                                                  __bf16* __restrict__ Cp) {
    __shared__ __attribute__((aligned(16))) __bf16 As[2 * ATILE];
    __shared__ __attribute__((aligned(16))) __bf16 Bs[2 * ATILE];

    const int tid  = threadIdx.x;
    const int wave = tid >> 6, lane = tid & 63;
    const int q    = lane >> 4, r16 = lane & 15;
    const int m0 = blockIdx.x * 256, n0 = blockIdx.y * 256, k0 = blockIdx.z * KS;
    const int wm = wave >> 2, wn = wave & 3;     // 2x4 waves; per-wave 128x64 out

    const int sr = tid >> 3;                           // 0..63
    const int sc = (tid & 7) ^ ((tid >> 4) & 7);       // de-swizzled source col
    const __bf16* gB0 = B + (size_t)(n0 + sr) * KT       + k0 + sc * 8;
    const __bf16* gB1 = B + (size_t)(n0 + 64  + sr) * KT + k0 + sc * 8;
    const __bf16* gB2 = B + (size_t)(n0 + 128 + sr) * KT + k0 + sc * 8;
    const __bf16* gB3 = B + (size_t)(n0 + 192 + sr) * KT + k0 + sc * 8;
    // silu gll16 source (row stride 512; per-tile kk added later; NO k0)
    const __bf16* gS0 = Sg + (size_t)(m0 + sr) * 512       + sc * 8;
    const __bf16* gS1 = Sg + (size_t)(m0 + 64  + sr) * 512 + sc * 8;
    const __bf16* gS2 = Sg + (size_t)(m0 + 128 + sr) * 512 + sc * 8;
    const __bf16* gS3 = Sg + (size_t)(m0 + 192 + sr) * 512 + sc * 8;
    // basis x sources: thread t needs x[m0 + sr + {0,64,128,192}][xcol],
    // xcol = (kbase>>4) + (sc>>1); j-half = 8*(sc&1).
    const float* xp0 = xg + (size_t)(m0 + sr) * 512       + (sc >> 1);
    const float* xp1 = xg + (size_t)(m0 + 64  + sr) * 512 + (sc >> 1);
    const float* xp2 = xg + (size_t)(m0 + 128 + sr) * 512 + (sc >> 1);
    const float* xp3 = xg + (size_t)(m0 + 192 + sr) * 512 + (sc >> 1);
    const float j0f  = (float)(8 * (sc & 1));

    f32x4 acc[8][4] = {};

    // read offsets (XOR de-swizzle, = R9)
    const int swl = (r16 >> 1) & 7;
    const int qx0 = ((q)     ^ swl) * 8;         // ks=0 chunk
    const int qx1 = ((4 + q) ^ swl) * 8;         // ks=1 chunk
    const int aro = (wm * 128 + r16) * 64;
    const int bro = (wn * 64  + r16) * 64;

    // 8 basis values (j = j0..j0+7) for one x value
    auto basis8 = [&](float xv) -> bf16x8 {
        const float zc = 3.75f * xv + 7.5f - j0f;    // z_j = zc - d
        bf16x8 o;
#pragma unroll
        for (int d = 0; d < 8; ++d) { float z = zc - (float)d; o[d] = (__bf16)__expf(-z * z); }
        return o;
    };

    // prologue: B(0) via gll16 (gB* already at k0); A(0) basis (tile 0 is
    // basis for all z: max k0 = 7616 < 8192), lane-linear stores into slot 0.
    // Also pre-load x for tile 0's stores (A(1) at col (k0+64)>>4).
    float xA, xB, xC, xD;
    {
        const int xo = k0 >> 4;
        float x0 = xp0[xo], x1 = xp1[xo], x2 = xp2[xo], x3 = xp3[xo];
        gll16(gB0, &Bs[(size_t)tid * 8]);
        gll16(gB1, &Bs[(size_t)(512 + tid) * 8]);
        gll16(gB2, &Bs[(size_t)(1024 + tid) * 8]);
        gll16(gB3, &Bs[(size_t)(1536 + tid) * 8]);
        *(bf16x8*)(As + (size_t)tid * 8)          = basis8(x0);
        *(bf16x8*)(As + (size_t)(512 + tid) * 8)  = basis8(x1);
        *(bf16x8*)(As + (size_t)(1024 + tid) * 8) = basis8(x2);
        *(bf16x8*)(As + (size_t)(1536 + tid) * 8) = basis8(x3);
        const int xo1 = (k0 + 64) >> 4;          // always < 512 (k0 max 7616)
        xA = xp0[xo1]; xB = xp1[xo1]; xC = xp2[xo1]; xD = xp3[xo1];
    }
    __syncthreads();

    bf16x8 a[8], b[4];
    for (int u = 0; u < NT2; ++u) {
        const int s   = u & 1;
        const int cbo = s * ATILE;               // compute slot (tile u)
        const int so1 = (s ^ 1) * ATILE;         // staging slot (tile u+1)
        const int k1  = (u + 1) * 64;            // tile-local (gB*: k0 baked in)
        const int kn  = k0 + k1;                 // GLOBAL k-base of tile u+1
        const bool nb = kn < 8192;               // tile u+1 is basis?
        const int kk  = kn - 8192;               // silu col base (when !nb)
        const int k2g = kn + 64;                 // GLOBAL k-base of tile u+2
        const bool nb2 = k2g < 8192;             // tile u+2 is basis?
        float t0, t1, t2, t3;                    // x loads for tile u+2
        // Tail (u+1==NT2): basis z<7 writes a never-consumed tile from valid
        // x cols (<=480); silu z=7 reads <=512 elems past Asilu rows ->
        // lands in Bm (mapped, unused); B reads <=128 B past the slice ->
        // mapped, never consumed.

        // ======== P0: ks=0 (12 ds_read, all DMA, 32 MFMA) ========
#pragma unroll
        for (int mi = 0; mi < 8; ++mi) a[mi] = *(const bf16x8*)(As + cbo + aro + mi * 1024 + qx0);
#pragma unroll
        for (int ni = 0; ni < 4; ++ni) b[ni] = *(const bf16x8*)(Bs + cbo + bro + ni * 1024 + qx0);
        gll16(gB0 + k1, &Bs[(size_t)(so1 + tid * 8)]);
        gll16(gB1 + k1, &Bs[(size_t)(so1 + (512 + tid) * 8)]);
        gll16(gB2 + k1, &Bs[(size_t)(so1 + (1024 + tid) * 8)]);
        gll16(gB3 + k1, &Bs[(size_t)(so1 + (1536 + tid) * 8)]);
        if (nb) {                                // basis stores pt1 (x from last tile)
            *(bf16x8*)(As + so1 + (size_t)tid * 8)          = basis8(xA);
            *(bf16x8*)(As + so1 + (size_t)(1024 + tid) * 8) = basis8(xC);
        } else {                                 // silu DMA (z=7)
            gll16(gS0 + kk, &As[(size_t)(so1 + tid * 8)]);
            gll16(gS1 + kk, &As[(size_t)(so1 + (512 + tid) * 8)]);
            gll16(gS2 + kk, &As[(size_t)(so1 + (1024 + tid) * 8)]);
            gll16(gS3 + kk, &As[(size_t)(so1 + (1536 + tid) * 8)]);
        }
        if (nb2) {                               // issue x loads for tile u+2
            const int xo = k2g >> 4;
            t0 = xp0[xo]; t1 = xp1[xo]; t2 = xp2[xo]; t3 = xp3[xo];
        }
        __builtin_amdgcn_s_setprio(1);
#pragma unroll
        for (int mi = 0; mi < 8; ++mi)
#pragma unroll
            for (int ni = 0; ni < 4; ++ni)
                acc[mi][ni] = __builtin_amdgcn_mfma_f32_16x16x32_bf16(a[mi], b[ni], acc[mi][ni], 0, 0, 0);
        __builtin_amdgcn_s_setprio(0);
        __builtin_amdgcn_s_barrier();

        // ======== P1: ks=1 (12 ds_read, basis pt2, 32 MFMA) ========
#pragma unroll
        for (int mi = 0; mi < 8; ++mi) a[mi] = *(const bf16x8*)(As + cbo + aro + mi * 1024 + qx1);
#pragma unroll
        for (int ni = 0; ni < 4; ++ni) b[ni] = *(const bf16x8*)(Bs + cbo + bro + ni * 1024 + qx1);
        if (nb) {                                // basis stores pt2
            *(bf16x8*)(As + so1 + (size_t)(512 + tid) * 8)  = basis8(xB);
            *(bf16x8*)(As + so1 + (size_t)(1536 + tid) * 8) = basis8(xD);
        }
        __builtin_amdgcn_s_setprio(1);
#pragma unroll
        for (int mi = 0; mi < 8; ++mi)
#pragma unroll
            for (int ni = 0; ni < 4; ++ni)
                acc[mi][ni] = __builtin_amdgcn_mfma_f32_16x16x32_bf16(a[mi], b[ni], acc[mi][ni], 0, 0, 0);
        __builtin_amdgcn_s_setprio(0);
        if (nb2) { xA = t0; xB = t1; xC = t2; xD = t3; }   // commit for tile u+1
        // tile end: compiler-understood full drain + barrier. Publishes the
        // basis ds_writes and drains the DMA (all issued in P0).
        __syncthreads();
    }

    // epilogue: C/D layout col=lane&15, row=(lane>>4)*4+reg; bf16 partials
    __bf16* Cb = Cp + (size_t)blockIdx.z * CPE;
#pragma unroll
    for (int mi = 0; mi < 8; ++mi) {
        const int row = m0 + wm * 128 + mi * 16 + q * 4;
#pragma unroll
        for (int ni = 0; ni < 4; ++ni) {
            const int col = n0 + wn * 64 + ni * 16 + r16;
#pragma unroll
            for (int r = 0; r < 4; ++r)
                Cb[(size_t)(row + r) * 512 + col] = (__bf16)acc[mi][ni][r];
        }
    }
}

// ---- kernel 3: sum 8 bf16 partials + LayerNorm, one wave per row ----------
__global__ void ln_kernel(const __bf16* __restrict__ Cp, const float* __restrict__ gamma,
                          const float* __restrict__ beta, float* __restrict__ out) {
    const int tid  = threadIdx.x;
    const int wave = tid >> 6, lane = tid & 63;
    const int row  = blockIdx.x * 4 + wave;
    const size_t base = (size_t)row * 512 + lane * 8;   // 8 contiguous cols/lane

    float v[8] = {};
    float s = 0.f, s2 = 0.f;
#pragma unroll
    for (int z = 0; z < SPLITS; ++z) {
        bf16x8 p = *(const bf16x8*)(Cp + (size_t)z * CPE + base);
#pragma unroll
        for (int j = 0; j < 8; ++j) v[j] += (float)p[j];
    }
#pragma unroll
    for (int j = 0; j < 8; ++j) { s += v[j]; s2 += v[j] * v[j]; }
#pragma unroll
    for (int m = 32; m >= 1; m >>= 1) {
        s  += __shfl_xor(s, m);
        s2 += __shfl_xor(s2, m);
    }
    const float mean = s * (1.0f / 512.0f);
    const float var  = s2 * (1.0f / 512.0f) - mean * mean;
    const float rs   = rsqrtf(var + 1e-5f);
    float4 o0, o1;
    const float4 g0 = *(const float4*)&gamma[lane * 8];
    const float4 g1 = *(const float4*)&gamma[lane * 8 + 4];
    const float4 b0 = *(const float4*)&beta[lane * 8];
    const float4 b1 = *(const float4*)&beta[lane * 8 + 4];
    o0.x = (v[0] - mean) * rs * g0.x + b0.x;
    o0.y = (v[1] - mean) * rs * g0.y + b0.y;
    o0.z = (v[2] - mean) * rs * g0.z + b0.z;
    o0.w = (v[3] - mean) * rs * g0.w + b0.w;
    o1.x = (v[4] - mean) * rs * g1.x + b1.x;
    o1.y = (v[5] - mean) * rs * g1.y + b1.y;
    o1.z = (v[6] - mean) * rs * g1.z + b1.z;
    o1.w = (v[7] - mean) * rs * g1.w + b1.w;
    *(float4*)&out[base]     = o0;
    *(float4*)&out[base + 4] = o1;
}

extern "C" void kernel_launch(void* const* d_in, const int* in_sizes, int n_in,
                              void* d_out, int out_size, void* d_ws, size_t ws_size,
                              hipStream_t stream) {
    const float* x     = (const float*)d_in[0];
    const float* W     = (const float*)d_in[1];
    const float* Wb    = (const float*)d_in[2];
    const float* gamma = (const float*)d_in[3];
    const float* beta  = (const float*)d_in[4];
    float* out = (float*)d_out;

    char* ws = (char*)d_ws;
    __bf16* Asilu = (__bf16*)ws;                     //  4,194,304 B
    __bf16* Bm    = (__bf16*)(ws + 4194304);         //  8,912,896 B
    __bf16* Cp    = (__bf16*)(ws + 13107200);        // 33,554,432 B

    prep_AB<<<1024 + 4352, 256, 0, stream>>>(x, W, Wb, Asilu, Bm);
    dim3 g(16, 2, SPLITS);
    gemm_bt<<<g, 512, 0, stream>>>(x, Asilu, Bm, Cp);
    ln_kernel<<<1024, 256, 0, stream>>>(Cp, gamma, beta, out);
}